// Round 15
// baseline (34.738 us; speedup 1.0000x reference)
//
#include <hip/hip_runtime.h>

// MPS batched contraction via SITE PAIRING (R9/R11/R13-verified):
// G_P[l][pq][d] = Σ_m A_{2P}[l,p,m] A_{2P+1}[m,q,d],  xx[pq] = x_p * y_q,
// left'' = G_P(xx) left.  32 pairs, K=128 each, 32x32x16 f16 MFMA:
//   A-op (G): row d = lane&31, k = 8*(lane>>5) + e
//   B-op (U): col b = lane&31, same k;  C/D: col = lane&31,
//   row l = (reg&3) + 8*(reg>>2) + 4*(lane>>5)
// G-frag kf = pq*2+lh encodes l = 16*lh + (e&3) + 8*(e>>2) + 4*h =>
//   U_frag(kf) = f16(left[e + 8*lh]) * xx[pq]  -- SAME LANE.
//
// R15 = R13 (28.8us best) + ONE change: the per-pair 8-deep dependent MFMA
// chain (est ~1100cy latency, the config-invariant wall R1-R14 never moved)
// is tree-reduced into FOUR independent 2-deep chains + 3 vector adds:
//   acc = (t0+t1) + (t2+t3),  critical path ~330cy.
// Register cost: 4 live floatx16 temps -> launch_bounds(256,1) lifts the
// 128-VGPR cap (LDS 66KB already pins occupancy at 2 blocks/CU = 2/SIMD,
// which only needs <=256 VGPR). VGPR_Count is the success tell (~150-200).

typedef _Float16 half8 __attribute__((ext_vector_type(8)));
typedef _Float16 half4 __attribute__((ext_vector_type(4)));
typedef float floatx16 __attribute__((ext_vector_type(16)));
typedef float f32x4 __attribute__((ext_vector_type(4)));

#define NPAIRS 32
#define GCH 8192        // halfs per 2-pair G chunk = 16 KB
#define XSTRIDE 129     // padded half4 units per quad line (bank spread)

// ---------------- prep: pair products + fragment packing (R11-proven) -----
__global__ void mps_prep_pair(const float* __restrict__ A, _Float16* __restrict__ Gf) {
    __shared__ float sA0[2048], sA1[2048], sG[4096];
    const int P = blockIdx.x, tid = threadIdx.x;      // 256 threads
    const float* a0p = A + (size_t)(2 * P) * 2048;
    const float* a1p = A + (size_t)(2 * P + 1) * 2048;
#pragma unroll
    for (int i = 0; i < 8; ++i) {
        sA0[tid + 256 * i] = a0p[tid + 256 * i];
        sA1[tid + 256 * i] = a1p[tid + 256 * i];
    }
    __syncthreads();
    {   // thread -> (l, pq, d-half): 16 outputs, dot over m=32 in f32
        const int l = tid >> 3, pq = (tid >> 1) & 3, dh16 = (tid & 1) * 16;
        const int p = pq >> 1, q = pq & 1;
        float accv[16];
#pragma unroll
        for (int dd = 0; dd < 16; ++dd) accv[dd] = 0.f;
        for (int m = 0; m < 32; ++m) {
            const float av = sA0[l * 64 + p * 32 + m];
            const float* bp = &sA1[m * 64 + q * 32 + dh16];
#pragma unroll
            for (int dd = 0; dd < 16; ++dd) accv[dd] += av * bp[dd];
        }
#pragma unroll
        for (int dd = 0; dd < 16; ++dd) sG[l * 128 + pq * 32 + dh16 + dd] = accv[dd];
    }
    __syncthreads();
    const int lane = tid & 63;
    const int h    = lane >> 5;
    const int d    = lane & 31;
#pragma unroll
    for (int pass = 0; pass < 2; ++pass) {
        const int kf = (tid >> 6) + pass * 4;         // 0..7
        const int pq = kf >> 1, lh = kf & 1;
        half8 v;
#pragma unroll
        for (int e = 0; e < 8; ++e) {
            const int l = 16 * lh + (e & 3) + 8 * (e >> 2) + 4 * h;
            v[e] = (_Float16)sG[l * 128 + pq * 32 + d];
        }
        reinterpret_cast<half8*>(Gf)[((size_t)P * 8 + kf) * 64 + lane] = v;
    }
}

// ---------------- main kernel ----------------
#define MF32(A_, B_, C_) __builtin_amdgcn_mfma_f32_32x32x16_f16(A_, B_, C_, 0, 0, 0)

// Stage 2-pair G chunk C into buffer BUF: 16 recs of 1KB, 4 waves x 4 recs.
#define STAGEG(C, BUF)                                                        \
    {                                                                         \
        _Pragma("unroll")                                                     \
        for (int r_ = 0; r_ < 4; ++r_) {                                      \
            const int rec_ = r_ * 4 + wid;                                    \
            const _Float16* g_ = Gf + (size_t)(C) * GCH + rec_ * 512 + lane * 8; \
            __builtin_amdgcn_global_load_lds(                                 \
                (const __attribute__((address_space(1))) void*)g_,            \
                (__attribute__((address_space(3))) void*)&smG[(BUF) * GCH + rec_ * 512], \
                16, 0, 0);                                                    \
        }                                                                     \
    }

// One pair: x quad from LDS, 8 JIT G ds_reads, FA cvt from acc, then FOUR
// independent 2-deep MFMA chains tree-added (critical path ~2 MFMA + 2 add).
#define PAIRDO(BUF, LP, P)                                                    \
    {                                                                         \
        const half4 xq_ = smX[(P) * XSTRIDE + r];                             \
        const _Float16 w00_ = xq_[0] * xq_[2];                                \
        const _Float16 w01_ = xq_[0] * xq_[3];                                \
        const _Float16 w10_ = xq_[1] * xq_[2];                                \
        const _Float16 w11_ = xq_[1] * xq_[3];                                \
        half8 G_[8];                                                          \
        _Pragma("unroll")                                                     \
        for (int f_ = 0; f_ < 8; ++f_)                                        \
            G_[f_] = *(const half8*)&smG[(BUF) * GCH + (((LP) * 8 + f_) * 64 + lane) * 8]; \
        half8 FA0_, FA1_;                                                     \
        _Pragma("unroll")                                                     \
        for (int i_ = 0; i_ < 8; ++i_) {                                      \
            FA0_[i_] = (_Float16)acc[i_];                                     \
            FA1_[i_] = (_Float16)acc[8 + i_];                                 \
        }                                                                     \
        floatx16 t0_, t1_, t2_, t3_;                                          \
        t0_ = MF32(G_[0], FA0_ * w00_, zv);                                   \
        t1_ = MF32(G_[2], FA0_ * w01_, zv);                                   \
        t2_ = MF32(G_[4], FA0_ * w10_, zv);                                   \
        t3_ = MF32(G_[6], FA0_ * w11_, zv);                                   \
        t0_ = MF32(G_[1], FA1_ * w00_, t0_);                                  \
        t1_ = MF32(G_[3], FA1_ * w01_, t1_);                                  \
        t2_ = MF32(G_[5], FA1_ * w10_, t2_);                                  \
        t3_ = MF32(G_[7], FA1_ * w11_, t3_);                                  \
        acc = (t0_ + t1_) + (t2_ + t3_);                                      \
    }

// One 2-pair chunk: stage next chunk up front, compute both pairs, barrier.
#define CHUNK(C, BUF)                                                         \
    {                                                                         \
        if ((C) < 15) STAGEG((C) + 1, 1 - (BUF));                             \
        PAIRDO(BUF, 0, 2 * (C))                                               \
        PAIRDO(BUF, 1, 2 * (C) + 1)                                           \
        __syncthreads();                                                      \
    }

__global__ __launch_bounds__(256, 1) void mps_main(const float* __restrict__ x,
                                                   const _Float16* __restrict__ Gf,
                                                   float* __restrict__ out) {
    __shared__ __align__(16) _Float16 smG[2 * GCH];       // 32 KB
    __shared__ __align__(8)  half4    smX[32 * XSTRIDE];  // 33 KB, [quad][row]

    const int tid  = threadIdx.x;
    const int lane = tid & 63;
    const int wid  = tid >> 6;                 // 0..3
    const int brow = blockIdx.x * 128;         // block's first batch row
    const int col  = lane & 31;
    const int r    = wid * 32 + col;           // this wave's row within block

    STAGEG(0, 0);

    // x -> LDS f16 transposed [quad][row]: coalesced f32x4 global reads
    // (flat quad index j: lane-consecutive addresses), free-2-way ds_writes.
#pragma unroll
    for (int i = 0; i < 16; ++i) {
        const int j   = i * 256 + tid;         // 0..4095
        const int row = j >> 5, q = j & 31;
        const f32x4 v = *(const f32x4*)(x + (size_t)(brow + row) * 128 + 4 * q);
        half4 hv;
        hv[0] = (_Float16)v[0]; hv[1] = (_Float16)v[1];
        hv[2] = (_Float16)v[2]; hv[3] = (_Float16)v[3];
        smX[q * XSTRIDE + row] = hv;
    }

    floatx16 zv;
#pragma unroll
    for (int i = 0; i < 16; ++i) zv[i] = 0.f;

    // acc = left[l], l = (reg&3) + 8*(reg>>2) + 4*(lane>>5)
    floatx16 acc;
#pragma unroll
    for (int i = 0; i < 16; ++i) acc[i] = 0.f;
    if (lane < 32) acc[0] = 1.f;               // left0 = e0

    __syncthreads();                            // x in LDS + G chunk 0 ready

    CHUNK(0, 0)   CHUNK(1, 1)   CHUNK(2, 0)   CHUNK(3, 1)
    CHUNK(4, 0)   CHUNK(5, 1)   CHUNK(6, 0)   CHUNK(7, 1)
    CHUNK(8, 0)   CHUNK(9, 1)   CHUNK(10, 0)  CHUNK(11, 1)
    CHUNK(12, 0)  CHUNK(13, 1)  CHUNK(14, 0)  CHUNK(15, 1)

    // out[b] = left_final[l=0]: reg 0, h=0 -> lanes 0..31
    if (lane < 32) out[brow + wid * 32 + lane] = acc[0];
}

extern "C" void kernel_launch(void* const* d_in, const int* in_sizes, int n_in,
                              void* d_out, int out_size, void* d_ws, size_t ws_size,
                              hipStream_t stream) {
    const float* x = (const float*)d_in[0];   // [65536][64][2] f32
    const float* A = (const float*)d_in[1];   // [64][32][2][32] f32
    float* outp = (float*)d_out;              // [65536] f32
    _Float16* Gf = (_Float16*)d_ws;           // 256 KB pair-fragment fp16

    hipLaunchKernelGGL(mps_prep_pair, dim3(NPAIRS), dim3(256), 0, stream, A, Gf);
    hipLaunchKernelGGL(mps_main, dim3(65536 / 128), dim3(256), 0, stream, x, Gf, outp);
}

// Round 16
// 30.163 us; speedup vs baseline: 1.1517x; 1.1517x over previous
//
#include <hip/hip_runtime.h>

// MPS batched contraction via SITE PAIRING (R9/R11/R13-verified):
// G_P[l][pq][d] = Σ_m A_{2P}[l,p,m] A_{2P+1}[m,q,d],  xx[pq] = x_p * y_q,
// left'' = G_P(xx) left.  32 pairs, K=128 each, 32x32x16 f16 MFMA:
//   A-op (G): row d = lane&31, k = 8*(lane>>5) + e
//   B-op (U): col b = lane&31, same k;  C/D: col = lane&31,
//   row l = (reg&3) + 8*(reg>>2) + 4*(lane>>5)
// G-frag kf = pq*2+lh encodes l = 16*lh + (e&3) + 8*(e>>2) + 4*h =>
//   U_frag(kf) = f16(left[e + 8*lh]) * xx[pq]  -- SAME LANE.
//
// R16 = R13 main kernel BYTE-IDENTICAL (28.8us best) + parallel prep.
// Old prep: 32 blocks (12% of CUs), ~160 LDS-operand reads x 32 m per
// thread ~ 3.5-5us serial prologue. New prep: 128 blocks, one per (P,pq):
// 32x32x32 f32 matmul with register-blocked dot (1 b32 + 1 b128 + 4 FMA
// per m), each block packs its own 2 kf-frags. Same ascending-m FMA order
// -> bit-identical G -> absmax unchanged.
// (Kept XSTRIDE=129: the transposed x-store would be a 32-way WRITE
// conflict without the pad -- stride 1032B -> banks cycle, 2-way free.)

typedef _Float16 half8 __attribute__((ext_vector_type(8)));
typedef _Float16 half4 __attribute__((ext_vector_type(4)));
typedef float floatx16 __attribute__((ext_vector_type(16)));
typedef float f32x4 __attribute__((ext_vector_type(4)));

#define NPAIRS 32
#define GCH 8192        // halfs per 2-pair G chunk = 16 KB
#define XSTRIDE 129     // padded half4 units per quad line (bank spread)

// ---------------- prep: one block per (pair, pq) -------------------------
// G_{P,pq}[l][d] = Σ_m A0[l][m] * A1[m][d]  (A0 = A[2P][:,p,:], A1 = A[2P+1][:,q,:])
__global__ void mps_prep_pair(const float* __restrict__ A, _Float16* __restrict__ Gf) {
    __shared__ float sA[1024];   // [l][m]
    __shared__ float sB[1024];   // [m][d]
    __shared__ float sG[1024];   // [l][d]
    const int blk = blockIdx.x;          // 0..127 = P*4 + pq
    const int P   = blk >> 2;
    const int pq  = blk & 3;
    const int p   = pq >> 1, q = pq & 1;
    const int tid = threadIdx.x;         // 0..255
    const int row = tid >> 3;            // 0..31
    const int c4  = (tid & 7) * 4;       // 0,4,...,28

    // loads: row-contiguous f32x4 (row stride 64 floats in A)
    *(f32x4*)&sA[row * 32 + c4] =
        *(const f32x4*)(A + ((size_t)(2 * P) * 32 + row) * 64 + p * 32 + c4);
    *(f32x4*)&sB[row * 32 + c4] =
        *(const f32x4*)(A + ((size_t)(2 * P + 1) * 32 + row) * 64 + q * 32 + c4);
    __syncthreads();

    // dot: thread owns (l=row, d=c4..c4+3); ascending m (order matches old prep)
    {
        f32x4 acc;
        acc[0] = 0.f; acc[1] = 0.f; acc[2] = 0.f; acc[3] = 0.f;
        for (int m = 0; m < 32; ++m) {
            const float av = sA[row * 32 + m];
            const f32x4 bv = *(const f32x4*)&sB[m * 32 + c4];
            acc[0] += av * bv[0]; acc[1] += av * bv[1];
            acc[2] += av * bv[2]; acc[3] += av * bv[3];
        }
        *(f32x4*)&sG[row * 32 + c4] = acc;
    }
    __syncthreads();

    // pack this block's 2 frags: kf = pq*2 + lh, lh = 0,1
    if (tid < 128) {
        const int lh   = tid >> 6;
        const int lane = tid & 63;
        const int h    = lane >> 5;
        const int d    = lane & 31;
        half8 v;
#pragma unroll
        for (int e = 0; e < 8; ++e) {
            const int l = 16 * lh + (e & 3) + 8 * (e >> 2) + 4 * h;
            v[e] = (_Float16)sG[l * 32 + d];
        }
        reinterpret_cast<half8*>(Gf)[((size_t)P * 8 + pq * 2 + lh) * 64 + lane] = v;
    }
}

// ---------------- main kernel (byte-identical to R13) ---------------------
#define MF32(A_, B_, C_) __builtin_amdgcn_mfma_f32_32x32x16_f16(A_, B_, C_, 0, 0, 0)

// Stage 2-pair G chunk C into buffer BUF: 16 recs of 1KB, 4 waves x 4 recs.
#define STAGEG(C, BUF)                                                        \
    {                                                                         \
        _Pragma("unroll")                                                     \
        for (int r_ = 0; r_ < 4; ++r_) {                                      \
            const int rec_ = r_ * 4 + wid;                                    \
            const _Float16* g_ = Gf + (size_t)(C) * GCH + rec_ * 512 + lane * 8; \
            __builtin_amdgcn_global_load_lds(                                 \
                (const __attribute__((address_space(1))) void*)g_,            \
                (__attribute__((address_space(3))) void*)&smG[(BUF) * GCH + rec_ * 512], \
                16, 0, 0);                                                    \
        }                                                                     \
    }

// One pair: x quad from LDS (b64, lanes 32-63 broadcast), 8 JIT G ds_reads,
// FA cvt from acc, 8-MFMA in-place chain.
#define PAIRDO(BUF, LP, P)                                                    \
    {                                                                         \
        const half4 xq_ = smX[(P) * XSTRIDE + r];                             \
        const _Float16 w00_ = xq_[0] * xq_[2];                                \
        const _Float16 w01_ = xq_[0] * xq_[3];                                \
        const _Float16 w10_ = xq_[1] * xq_[2];                                \
        const _Float16 w11_ = xq_[1] * xq_[3];                                \
        half8 G_[8];                                                          \
        _Pragma("unroll")                                                     \
        for (int f_ = 0; f_ < 8; ++f_)                                        \
            G_[f_] = *(const half8*)&smG[(BUF) * GCH + (((LP) * 8 + f_) * 64 + lane) * 8]; \
        half8 FA0_, FA1_;                                                     \
        _Pragma("unroll")                                                     \
        for (int i_ = 0; i_ < 8; ++i_) {                                      \
            FA0_[i_] = (_Float16)acc[i_];                                     \
            FA1_[i_] = (_Float16)acc[8 + i_];                                 \
        }                                                                     \
        floatx16 t_;                                                          \
        t_ = MF32(G_[0], FA0_ * w00_, zv);                                    \
        t_ = MF32(G_[1], FA1_ * w00_, t_);                                    \
        t_ = MF32(G_[2], FA0_ * w01_, t_);                                    \
        t_ = MF32(G_[3], FA1_ * w01_, t_);                                    \
        t_ = MF32(G_[4], FA0_ * w10_, t_);                                    \
        t_ = MF32(G_[5], FA1_ * w10_, t_);                                    \
        t_ = MF32(G_[6], FA0_ * w11_, t_);                                    \
        t_ = MF32(G_[7], FA1_ * w11_, t_);                                    \
        acc = t_;                                                             \
    }

// One 2-pair chunk: stage next chunk up front, compute both pairs, barrier.
#define CHUNK(C, BUF)                                                         \
    {                                                                         \
        if ((C) < 15) STAGEG((C) + 1, 1 - (BUF));                             \
        PAIRDO(BUF, 0, 2 * (C))                                               \
        PAIRDO(BUF, 1, 2 * (C) + 1)                                           \
        __syncthreads();                                                      \
    }

__global__ __launch_bounds__(256, 2) void mps_main(const float* __restrict__ x,
                                                   const _Float16* __restrict__ Gf,
                                                   float* __restrict__ out) {
    __shared__ __align__(16) _Float16 smG[2 * GCH];       // 32 KB
    __shared__ __align__(8)  half4    smX[32 * XSTRIDE];  // 33 KB, [quad][row]

    const int tid  = threadIdx.x;
    const int lane = tid & 63;
    const int wid  = tid >> 6;                 // 0..3
    const int brow = blockIdx.x * 128;         // block's first batch row
    const int col  = lane & 31;
    const int r    = wid * 32 + col;           // this wave's row within block

    STAGEG(0, 0);

    // x -> LDS f16 transposed [quad][row]: coalesced f32x4 global reads
    // (flat quad index j: lane-consecutive addresses), free-2-way ds_writes.
#pragma unroll
    for (int i = 0; i < 16; ++i) {
        const int j   = i * 256 + tid;         // 0..4095
        const int row = j >> 5, q = j & 31;
        const f32x4 v = *(const f32x4*)(x + (size_t)(brow + row) * 128 + 4 * q);
        half4 hv;
        hv[0] = (_Float16)v[0]; hv[1] = (_Float16)v[1];
        hv[2] = (_Float16)v[2]; hv[3] = (_Float16)v[3];
        smX[q * XSTRIDE + row] = hv;
    }

    floatx16 zv;
#pragma unroll
    for (int i = 0; i < 16; ++i) zv[i] = 0.f;

    // acc = left[l], l = (reg&3) + 8*(reg>>2) + 4*(lane>>5)
    floatx16 acc;
#pragma unroll
    for (int i = 0; i < 16; ++i) acc[i] = 0.f;
    if (lane < 32) acc[0] = 1.f;               // left0 = e0

    __syncthreads();                            // x in LDS + G chunk 0 ready

    CHUNK(0, 0)   CHUNK(1, 1)   CHUNK(2, 0)   CHUNK(3, 1)
    CHUNK(4, 0)   CHUNK(5, 1)   CHUNK(6, 0)   CHUNK(7, 1)
    CHUNK(8, 0)   CHUNK(9, 1)   CHUNK(10, 0)  CHUNK(11, 1)
    CHUNK(12, 0)  CHUNK(13, 1)  CHUNK(14, 0)  CHUNK(15, 1)

    // out[b] = left_final[l=0]: reg 0, h=0 -> lanes 0..31
    if (lane < 32) out[brow + wid * 32 + lane] = acc[0];
}

extern "C" void kernel_launch(void* const* d_in, const int* in_sizes, int n_in,
                              void* d_out, int out_size, void* d_ws, size_t ws_size,
                              hipStream_t stream) {
    const float* x = (const float*)d_in[0];   // [65536][64][2] f32
    const float* A = (const float*)d_in[1];   // [64][32][2][32] f32
    float* outp = (float*)d_out;              // [65536] f32
    _Float16* Gf = (_Float16*)d_ws;           // 256 KB pair-fragment fp16

    hipLaunchKernelGGL(mps_prep_pair, dim3(NPAIRS * 4), dim3(256), 0, stream, A, Gf);
    hipLaunchKernelGGL(mps_main, dim3(65536 / 128), dim3(256), 0, stream, x, Gf, outp);
}